// Round 1
// baseline (291.335 us; speedup 1.0000x reference)
//
#include <hip/hip_runtime.h>
#include <stdint.h>

// ---------------- problem constants ----------------
#define NB   8      // batch
#define SS   2048   // seq
#define DD   1024   // embd
#define BOT  400    // bottleneck
#define BOTP 512    // bottleneck padded to x128 (padded weights = 0 -> h = relu(0) = 0 -> no effect)
#define NAD  25     // adapters
#define MM   (NB*SS)
#define LN_EPS 1e-5f

typedef __attribute__((ext_vector_type(8))) short bf8_t;  // 8 bf16 values (4 VGPRs)
typedef __attribute__((ext_vector_type(4))) float fx4;

__device__ __forceinline__ unsigned short f2bf(float f) {
  unsigned int u = __float_as_uint(f);
  u = (u + 0x7FFFu + ((u >> 16) & 1u)) >> 16;   // RNE bf16
  return (unsigned short)u;
}

// async global->LDS, 16B per lane. LDS dest must be wave-uniform base (+lane*16 implicit).
// addrspace conversion via integer round-trip: generic->AS(1) is identity,
// generic->AS(3) is low-32-bit truncation (same as addrspacecast lowering).
__device__ __forceinline__ void gload16(void* lds, const void* g) {
  __builtin_amdgcn_global_load_lds(
      (const __attribute__((address_space(1))) void*)(uintptr_t)g,
      (__attribute__((address_space(3))) void*)(uint32_t)(uintptr_t)lds,
      16, 0, 0);
}

// ---------------- kernel 1: mix weights (alpha-weighted sums), cast to bf16, pad ----------------
// blocks 0..511   : W_down [BOTP=512][1024] bf16 (rows >=400 zero)
// blocks 512..1023: W_up   [1024][BOTP=512] bf16 (cols >=400 zero)
// blocks 1024..1031: wln[1024], bln[1024] f32
__global__ __launch_bounds__(256) void mix_kernel(
    const float* __restrict__ alphas,
    const float* __restrict__ WdAll, const float* __restrict__ WuAll,
    const float* __restrict__ wlnAll, const float* __restrict__ blnAll,
    unsigned short* __restrict__ Wd, unsigned short* __restrict__ Wu,
    float* __restrict__ wln, float* __restrict__ bln)
{
  __shared__ float a[NAD];
  const int tid = threadIdx.x;
  if (tid < NAD) a[tid] = alphas[tid];
  __syncthreads();
  const int bid = blockIdx.x;
  if (bid < 512) {                       // W_down: 512*1024 outs, 4 per thread
    int g  = bid * 256 + tid;            // 0..131071
    int o  = g >> 8;                     // row (bottleneck idx), /256 groups per row
    int dg = g & 255;                    // float4 group along D
    float4 acc = {0.f, 0.f, 0.f, 0.f};
    if (o < BOT) {
#pragma unroll
      for (int n = 0; n < NAD; ++n) {
        const float4 v = *(const float4*)(WdAll + ((size_t)n * BOT + o) * DD + dg * 4);
        acc.x += a[n] * v.x; acc.y += a[n] * v.y; acc.z += a[n] * v.z; acc.w += a[n] * v.w;
      }
    }
    ushort4 u;
    u.x = f2bf(acc.x); u.y = f2bf(acc.y); u.z = f2bf(acc.z); u.w = f2bf(acc.w);
    *(ushort4*)(Wd + (size_t)o * DD + dg * 4) = u;
  } else if (bid < 1024) {               // W_up: 1024*512 outs, 4 per thread
    int g  = (bid - 512) * 256 + tid;    // 0..131071
    int d  = g >> 7;                     // row (embd idx), 128 groups per padded row
    int bg = g & 127;                    // float4 group along BOTP
    float4 acc = {0.f, 0.f, 0.f, 0.f};
    if (bg < 100) {                      // 400/4 valid groups
#pragma unroll
      for (int n = 0; n < NAD; ++n) {
        const float4 v = *(const float4*)(WuAll + ((size_t)n * DD + d) * BOT + bg * 4);
        acc.x += a[n] * v.x; acc.y += a[n] * v.y; acc.z += a[n] * v.z; acc.w += a[n] * v.w;
      }
    }
    ushort4 u;
    u.x = f2bf(acc.x); u.y = f2bf(acc.y); u.z = f2bf(acc.z); u.w = f2bf(acc.w);
    *(ushort4*)(Wu + (size_t)d * BOTP + bg * 4) = u;
  } else {                               // wln / bln
    int i = (bid - 1024) * 256 + tid;    // 0..2047
    const float* src = (i < DD) ? wlnAll : blnAll;
    int j = (i < DD) ? i : (i - DD);
    float s = 0.f;
#pragma unroll
    for (int n = 0; n < NAD; ++n) s += a[n] * src[(size_t)n * DD + j];
    if (i < DD) wln[j] = s; else bln[j] = s;
  }
}

// ---------------- kernel 2: LN partial stats (sum, sumsq) per (batch, chunk) ----------------
__global__ __launch_bounds__(256) void stats_kernel(const float* __restrict__ x,
                                                    float* __restrict__ partials)
{
  const int b = blockIdx.y, c = blockIdx.x;  // 8 x 64
  const float4* xb = (const float4*)(x + (size_t)b * SS * DD) + (size_t)c * 8192;
  float s = 0.f, q = 0.f;
  for (int i = threadIdx.x; i < 8192; i += 256) {
    float4 v = xb[i];
    s += v.x + v.y + v.z + v.w;
    q += v.x * v.x + v.y * v.y + v.z * v.z + v.w * v.w;
  }
#pragma unroll
  for (int off = 32; off > 0; off >>= 1) { s += __shfl_down(s, off); q += __shfl_down(q, off); }
  __shared__ float red[8];
  const int wave = threadIdx.x >> 6, lane = threadIdx.x & 63;
  if (!lane) { red[wave] = s; red[wave + 4] = q; }
  __syncthreads();
  if (!threadIdx.x) {
    partials[(b * 64 + c) * 2]     = red[0] + red[1] + red[2] + red[3];
    partials[(b * 64 + c) * 2 + 1] = red[4] + red[5] + red[6] + red[7];
  }
}

// ---------------- kernel 3: normalize -> bf16 x_hat ----------------
__global__ __launch_bounds__(256) void norm_kernel(const float* __restrict__ x,
    const float* __restrict__ partials, const float* __restrict__ wln,
    const float* __restrict__ bln, unsigned short* __restrict__ xn)
{
  const int b = blockIdx.y;
  double s = 0.0, q = 0.0;
#pragma unroll 8
  for (int i = 0; i < 64; ++i) {
    s += partials[(b * 64 + i) * 2];
    q += partials[(b * 64 + i) * 2 + 1];
  }
  const double inv = 1.0 / ((double)SS * DD);
  const float mu  = (float)(s * inv);
  const float var = (float)(q * inv) - mu * mu;
  const float rs  = rsqrtf(var + LN_EPS);

  const size_t base = (size_t)b * SS * DD;
  const int idx = blockIdx.x * 256 + threadIdx.x;      // float4 index within batch
  const float4 v  = *(const float4*)(x + base + (size_t)idx * 4);
  const int dg = idx & 255;                            // D=1024 -> 256 float4 groups/row
  const float4 w  = *(const float4*)(wln + dg * 4);
  const float4 bb = *(const float4*)(bln + dg * 4);
  ushort4 u;
  u.x = f2bf((v.x - mu) * rs * w.x + bb.x);
  u.y = f2bf((v.y - mu) * rs * w.y + bb.y);
  u.z = f2bf((v.z - mu) * rs * w.z + bb.z);
  u.w = f2bf((v.w - mu) * rs * w.w + bb.w);
  *(ushort4*)(xn + base + (size_t)idx * 4) = u;
}

// ---------------- kernels 4/5: 128x128 MFMA GEMM, C = A[M,K] @ B[N,K]^T ----------------
// m97 structure: BK=32, 4 waves in 2x2, each wave 64x64 (4x4 frags of 16x16x32 bf16),
// global_load_lds width-16 staging, 2 barriers per K-step.
// RELU=true : C -> relu -> bf16 store (Cb), ldc=N
// RELU=false: C -> + Xres -> f32 store (Cf)
template <int K, bool RELU>
__global__ __launch_bounds__(256) void gemm_bt(
    const unsigned short* __restrict__ A, const unsigned short* __restrict__ Bm,
    const float* __restrict__ Xres, float* __restrict__ Cf,
    unsigned short* __restrict__ Cb, int N)
{
  __shared__ unsigned short As[128 * 32];
  __shared__ unsigned short Bs[128 * 32];
  const int tid  = threadIdx.x;
  const int wave = tid >> 6, lane = tid & 63;
  const int wr = wave >> 1, wc = wave & 1;
  const int nbn  = N >> 7;
  const int bcol = blockIdx.x % nbn, brow = blockIdx.x / nbn;
  const unsigned short* Ab = A + (size_t)brow * 128 * K;
  const unsigned short* Bb = Bm + (size_t)bcol * 128 * K;

  fx4 acc[4][4] = {};

  for (int k0 = 0; k0 < K; k0 += 32) {
#pragma unroll
    for (int i = 0; i < 2; ++i) {
      const int basee = (i * 256 + wave * 64) * 8;   // wave-uniform element base in tile
      const int e   = basee + lane * 8;
      const int row = e >> 5, col = e & 31;
      gload16(&As[basee], Ab + (size_t)row * K + k0 + col);
      gload16(&Bs[basee], Bb + (size_t)row * K + k0 + col);
    }
    __syncthreads();   // drains vmcnt before barrier (compiler-inserted)

    bf8_t af[4], bf[4];
#pragma unroll
    for (int m = 0; m < 4; ++m)
      af[m] = *(const bf8_t*)&As[(wr * 64 + m * 16 + (lane & 15)) * 32 + (lane >> 4) * 8];
#pragma unroll
    for (int n = 0; n < 4; ++n)
      bf[n] = *(const bf8_t*)&Bs[(wc * 64 + n * 16 + (lane & 15)) * 32 + (lane >> 4) * 8];
#pragma unroll
    for (int m = 0; m < 4; ++m)
#pragma unroll
      for (int n = 0; n < 4; ++n)
        acc[m][n] = __builtin_amdgcn_mfma_f32_16x16x32_bf16(af[m], bf[n], acc[m][n], 0, 0, 0);
    __syncthreads();
  }

  // epilogue: C/D layout col = lane&15, row = (lane>>4)*4 + j  (m89-verified)
  const int r0 = brow * 128 + wr * 64 + ((lane >> 4) << 2);
  const int c0 = bcol * 128 + wc * 64 + (lane & 15);
#pragma unroll
  for (int m = 0; m < 4; ++m) {
#pragma unroll
    for (int n = 0; n < 4; ++n) {
#pragma unroll
      for (int j = 0; j < 4; ++j) {
        const size_t off = (size_t)(r0 + m * 16 + j) * N + (c0 + n * 16);
        float v = acc[m][n][j];
        if (RELU) {
          v = v > 0.f ? v : 0.f;
          Cb[off] = f2bf(v);
        } else {
          Cf[off] = v + Xres[off];
        }
      }
    }
  }
}

// ---------------- launcher ----------------
extern "C" void kernel_launch(void* const* d_in, const int* in_sizes, int n_in,
                              void* d_out, int out_size, void* d_ws, size_t ws_size,
                              hipStream_t stream)
{
  const float* x      = (const float*)d_in[0];
  const float* alphas = (const float*)d_in[1];
  const float* WdAll  = (const float*)d_in[2];
  const float* WuAll  = (const float*)d_in[3];
  // d_in[4], d_in[5] (b_down_all, b_up_all) unused by reference
  const float* wlnAll = (const float*)d_in[6];
  const float* blnAll = (const float*)d_in[7];
  float* out = (float*)d_out;

  char* ws = (char*)d_ws;
  unsigned short* Wd  = (unsigned short*)ws;                     // 512*1024*2  = 1 MB
  unsigned short* Wu  = (unsigned short*)(ws + (1u << 20));      // 1024*512*2  = 1 MB
  float* wln          = (float*)(ws + (2u << 20));               // 4 KB
  float* bln          = wln + DD;                                // 4 KB
  float* partials     = bln + DD;                                // 8*64*2 f32 = 4 KB
  unsigned short* xn  = (unsigned short*)(ws + (3u << 20));      // 16384*1024*2 = 32 MB
  unsigned short* h   = (unsigned short*)(ws + (35u << 20));     // 16384*512*2  = 16 MB
  // total ws use: 51 MB

  mix_kernel<<<1032, 256, 0, stream>>>(alphas, WdAll, WuAll, wlnAll, blnAll, Wd, Wu, wln, bln);
  stats_kernel<<<dim3(64, 8), 256, 0, stream>>>(x, partials);
  norm_kernel<<<dim3(2048, 8), 256, 0, stream>>>(x, partials, wln, bln, xn);
  gemm_bt<1024, true ><<<128 * (BOTP / 128), 256, 0, stream>>>(xn, Wd, nullptr, nullptr, h, BOTP);
  gemm_bt<512,  false><<<128 * (DD / 128),   256, 0, stream>>>(h, Wu, x, out, nullptr, DD);
}